// Round 2
// baseline (489.453 us; speedup 1.0000x reference)
//
#include <hip/hip_runtime.h>

#define NH 32
#define HD 128
#define DPOS 4096
#define YSTR (HD + 4)   // 132 floats/row: 16B-aligned rows, bank-spread

__global__ __launch_bounds__(256) void fq_attn_kernel(
    const float* __restrict__ x,
    const float* __restrict__ pat,
    float* __restrict__ out) {
  __shared__ float Y[NH * YSTR];   // 16896 B
  __shared__ float S[NH * NH];     // 4096 B

  const int t = threadIdx.x;
  const int pos = blockIdx.x;

  const float4* __restrict__ x4 = reinterpret_cast<const float4*>(x + (size_t)pos * DPOS);
  const float4* __restrict__ p4 = reinterpret_cast<const float4*>(pat);

  // ---- Phase 1: Y = x * patterns (coalesced float4 loads) ----
  #pragma unroll
  for (int i = 0; i < 4; ++i) {
    const int fi = t + i * 256;      // float4 index within 1024
    const float4 xv = x4[fi];
    const float4 pv = p4[fi];
    const int h  = fi >> 5;          // 32 float4-chunks per head row
    const int dc = fi & 31;
    float* yr = &Y[h * YSTR + dc * 4];
    yr[0] = xv.x * pv.x;
    yr[1] = xv.y * pv.y;
    yr[2] = xv.z * pv.z;
    yr[3] = xv.w * pv.w;
  }
  __syncthreads();

  // ---- Phase 2: Gram S[h][g] = dot(Y[h], Y[g]), 2x2 tiles ----
  {
    const int th = t >> 4;           // 0..15
    const int tg = t & 15;           // 0..15
    const int h0 = th * 2, g0 = tg * 2;
    float a00 = 0.f, a01 = 0.f, a10 = 0.f, a11 = 0.f;
    #pragma unroll 4
    for (int s = 0; s < 32; ++s) {
      const int c = ((s + tg) & 31) * 4;   // d-interleave: <=2-way banks
      const float4 yh0 = *reinterpret_cast<const float4*>(&Y[ h0      * YSTR + c]);
      const float4 yh1 = *reinterpret_cast<const float4*>(&Y[(h0 + 1) * YSTR + c]);
      const float4 yg0 = *reinterpret_cast<const float4*>(&Y[ g0      * YSTR + c]);
      const float4 yg1 = *reinterpret_cast<const float4*>(&Y[(g0 + 1) * YSTR + c]);
      a00 += yh0.x * yg0.x + yh0.y * yg0.y + yh0.z * yg0.z + yh0.w * yg0.w;
      a01 += yh0.x * yg1.x + yh0.y * yg1.y + yh0.z * yg1.z + yh0.w * yg1.w;
      a10 += yh1.x * yg0.x + yh1.y * yg0.y + yh1.z * yg0.z + yh1.w * yg0.w;
      a11 += yh1.x * yg1.x + yh1.y * yg1.y + yh1.z * yg1.z + yh1.w * yg1.w;
    }
    S[ h0      * NH + g0    ] = a00;
    S[ h0      * NH + g0 + 1] = a01;
    S[(h0 + 1) * NH + g0    ] = a10;
    S[(h0 + 1) * NH + g0 + 1] = a11;
  }
  __syncthreads();

  // ---- Phase 3: row softmax (8 lanes per row, shuffle reduce) ----
  {
    const int r = t >> 3;            // 0..31
    const int j = t & 7;             // 0..7  (4 entries each)
    const float scale = 0.08838834764831843f;  // 1/sqrt(128)
    float v0 = S[r * NH + j * 4 + 0] * scale;
    float v1 = S[r * NH + j * 4 + 1] * scale;
    float v2 = S[r * NH + j * 4 + 2] * scale;
    float v3 = S[r * NH + j * 4 + 3] * scale;
    float m = fmaxf(fmaxf(v0, v1), fmaxf(v2, v3));
    m = fmaxf(m, __shfl_xor(m, 1));
    m = fmaxf(m, __shfl_xor(m, 2));
    m = fmaxf(m, __shfl_xor(m, 4));
    float e0 = __expf(v0 - m);
    float e1 = __expf(v1 - m);
    float e2 = __expf(v2 - m);
    float e3 = __expf(v3 - m);
    float sum = e0 + e1 + e2 + e3;
    sum += __shfl_xor(sum, 1);
    sum += __shfl_xor(sum, 2);
    sum += __shfl_xor(sum, 4);
    const float inv = 1.0f / sum;
    S[r * NH + j * 4 + 0] = e0 * inv;
    S[r * NH + j * 4 + 1] = e1 * inv;
    S[r * NH + j * 4 + 2] = e2 * inv;
    S[r * NH + j * 4 + 3] = e3 * inv;
  }
  __syncthreads();

  // ---- Phase 4: out[h][d] = sum_g A[h][g] * Y[g][d] ----
  {
    const int h = t >> 3;            // 0..31
    const int j = t & 7;             // 0..7 -> d = j*4 + k*32
    float4 acc0 = {0.f, 0.f, 0.f, 0.f};
    float4 acc1 = {0.f, 0.f, 0.f, 0.f};
    float4 acc2 = {0.f, 0.f, 0.f, 0.f};
    float4 acc3 = {0.f, 0.f, 0.f, 0.f};
    #pragma unroll 4
    for (int g = 0; g < NH; ++g) {
      const float a = S[h * NH + g];
      const float* yr = &Y[g * YSTR + j * 4];
      const float4 y0 = *reinterpret_cast<const float4*>(yr + 0 * 32);
      const float4 y1 = *reinterpret_cast<const float4*>(yr + 1 * 32);
      const float4 y2 = *reinterpret_cast<const float4*>(yr + 2 * 32);
      const float4 y3 = *reinterpret_cast<const float4*>(yr + 3 * 32);
      acc0.x += a * y0.x; acc0.y += a * y0.y; acc0.z += a * y0.z; acc0.w += a * y0.w;
      acc1.x += a * y1.x; acc1.y += a * y1.y; acc1.z += a * y1.z; acc1.w += a * y1.w;
      acc2.x += a * y2.x; acc2.y += a * y2.y; acc2.z += a * y2.z; acc2.w += a * y2.w;
      acc3.x += a * y3.x; acc3.y += a * y3.y; acc3.z += a * y3.z; acc3.w += a * y3.w;
    }
    float* op = out + (size_t)pos * DPOS + h * HD + j * 4;
    *reinterpret_cast<float4*>(op + 0 * 32) = acc0;
    *reinterpret_cast<float4*>(op + 1 * 32) = acc1;
    *reinterpret_cast<float4*>(op + 2 * 32) = acc2;
    *reinterpret_cast<float4*>(op + 3 * 32) = acc3;
  }
}

extern "C" void kernel_launch(void* const* d_in, const int* in_sizes, int n_in,
                              void* d_out, int out_size, void* d_ws, size_t ws_size,
                              hipStream_t stream) {
  const float* x   = reinterpret_cast<const float*>(d_in[0]);
  const float* pat = reinterpret_cast<const float*>(d_in[1]);
  float* out       = reinterpret_cast<float*>(d_out);
  const int n_pos = in_sizes[0] / DPOS;   // B*L = 16384
  fq_attn_kernel<<<dim3(n_pos), dim3(256), 0, stream>>>(x, pat, out);
}

// Round 3
// 424.234 us; speedup vs baseline: 1.1537x; 1.1537x over previous
//
#include <hip/hip_runtime.h>
#include <stdint.h>

#define NH 32
#define HD 128
#define DPOS 4096
#define YSTR 136      // shorts per Yhi/Ylo row: 272B = 17 granules (odd -> bank spread)
#define YTSTR 40      // shorts per Yt row: 80B (4 data granules + 1 pad granule)
#define SSTR 36       // floats per S row: 144B (16B-aligned rows, bank spread)

typedef __bf16 bf16x8 __attribute__((ext_vector_type(8)));
typedef float  f32x4  __attribute__((ext_vector_type(4)));

static __device__ __forceinline__ ushort f2bf(float f) {
  union { float f; uint32_t u; } v; v.f = f;
  uint32_t r = v.u + 0x7FFFu + ((v.u >> 16) & 1u);   // RNE
  return (ushort)(r >> 16);
}
static __device__ __forceinline__ float bf2f(ushort u) {
  union { uint32_t u; float f; } v; v.u = ((uint32_t)u) << 16;
  return v.f;
}

__global__ __launch_bounds__(256) void fq_attn_kernel(
    const float* __restrict__ x,
    const float* __restrict__ pat,
    float* __restrict__ out) {
  __shared__ ushort Yhi[NH * YSTR];   // 8704 B
  __shared__ ushort Ylo[NH * YSTR];   // 8704 B
  __shared__ ushort Yt [HD * YTSTR];  // 10240 B  (bf16 hi of Y, transposed [d][g])
  __shared__ float  S  [NH * SSTR];   // 4608 B
  // total ~32.3 KB -> 4 blocks/CU, 16 waves/CU

  const int t = threadIdx.x;
  const int pos = blockIdx.x;

  const float4* __restrict__ x4 = reinterpret_cast<const float4*>(x + (size_t)pos * DPOS);
  const float4* __restrict__ p4 = reinterpret_cast<const float4*>(pat);

  // ---- Phase 1: Y = x*pat -> bf16 hi/lo (row-major) + hi transposed (Yt) ----
  #pragma unroll
  for (int i = 0; i < 4; ++i) {
    const int fi = t + i * 256;          // float4 index in 0..1023
    const float4 xv = x4[fi];
    const float4 pv = p4[fi];
    const int h  = fi >> 5;              // head row 0..31
    const int dc = fi & 31;              // float4 chunk within row
    float y[4] = { xv.x * pv.x, xv.y * pv.y, xv.z * pv.z, xv.w * pv.w };
    ushort hi[4], lo[4];
    #pragma unroll
    for (int di = 0; di < 4; ++di) {
      hi[di] = f2bf(y[di]);
      lo[di] = f2bf(y[di] - bf2f(hi[di]));
    }
    // row-major vector writes (8B each)
    uint2 whi, wlo;
    whi.x = (uint32_t)hi[0] | ((uint32_t)hi[1] << 16);
    whi.y = (uint32_t)hi[2] | ((uint32_t)hi[3] << 16);
    wlo.x = (uint32_t)lo[0] | ((uint32_t)lo[1] << 16);
    wlo.y = (uint32_t)lo[2] | ((uint32_t)lo[3] << 16);
    *reinterpret_cast<uint2*>(&Yhi[h * YSTR + dc * 4]) = whi;
    *reinterpret_cast<uint2*>(&Ylo[h * YSTR + dc * 4]) = wlo;
    // transposed scalar writes (granule-rotated by (d>>2)&3 to spread banks)
    #pragma unroll
    for (int di = 0; di < 4; ++di) {
      const int d = dc * 4 + di;
      const int gq = ((h >> 3) + (d >> 2)) & 3;       // physical granule
      Yt[d * YTSTR + gq * 8 + (h & 7)] = hi[di];
    }
  }
  __syncthreads();

  // ---- Phase 2: Gram S = Y*Y^T via MFMA, split precision (3 terms) ----
  {
    const int w = t >> 6;                 // wave 0..3
    const int lane = t & 63;
    const int r = lane & 15, q = lane >> 4;
    const int hoff = (w >> 1) << 4;       // tile row base
    const int goff = (w & 1) << 4;        // tile col base
    const int arow = (hoff + r) * YSTR + q * 8;
    const int brow = (goff + r) * YSTR + q * 8;
    f32x4 acc = {0.f, 0.f, 0.f, 0.f};
    #pragma unroll
    for (int kk = 0; kk < 4; ++kk) {
      const bf16x8 ahi = *reinterpret_cast<const bf16x8*>(&Yhi[arow + kk * 32]);
      const bf16x8 alo = *reinterpret_cast<const bf16x8*>(&Ylo[arow + kk * 32]);
      const bf16x8 bhi = *reinterpret_cast<const bf16x8*>(&Yhi[brow + kk * 32]);
      const bf16x8 blo = *reinterpret_cast<const bf16x8*>(&Ylo[brow + kk * 32]);
      acc = __builtin_amdgcn_mfma_f32_16x16x32_bf16(ahi, bhi, acc, 0, 0, 0);
      acc = __builtin_amdgcn_mfma_f32_16x16x32_bf16(ahi, blo, acc, 0, 0, 0);
      acc = __builtin_amdgcn_mfma_f32_16x16x32_bf16(alo, bhi, acc, 0, 0, 0);
    }
    // C/D layout: col = lane&15, row = (lane>>4)*4 + reg   [verified m89]
    #pragma unroll
    for (int reg = 0; reg < 4; ++reg)
      S[(hoff + 4 * q + reg) * SSTR + goff + r] = acc[reg];
  }
  __syncthreads();

  // ---- Phase 3: row softmax (8 lanes/row, shuffle reduce) ----
  {
    const int r = t >> 3, j = t & 7;
    const float scale = 0.08838834764831843f;   // 1/sqrt(128)
    const float4 v = *reinterpret_cast<const float4*>(&S[r * SSTR + 4 * j]);
    float v0 = v.x * scale, v1 = v.y * scale, v2 = v.z * scale, v3 = v.w * scale;
    float m = fmaxf(fmaxf(v0, v1), fmaxf(v2, v3));
    m = fmaxf(m, __shfl_xor(m, 1));
    m = fmaxf(m, __shfl_xor(m, 2));
    m = fmaxf(m, __shfl_xor(m, 4));
    float e0 = __expf(v0 - m), e1 = __expf(v1 - m);
    float e2 = __expf(v2 - m), e3 = __expf(v3 - m);
    float sum = e0 + e1 + e2 + e3;
    sum += __shfl_xor(sum, 1);
    sum += __shfl_xor(sum, 2);
    sum += __shfl_xor(sum, 4);
    const float inv = 1.0f / sum;
    float4 o; o.x = e0 * inv; o.y = e1 * inv; o.z = e2 * inv; o.w = e3 * inv;
    *reinterpret_cast<float4*>(&S[r * SSTR + 4 * j]) = o;
  }
  __syncthreads();

  // ---- Phase 4: out = A * Y via MFMA (A split hi/lo in-register, Y = Yt bf16) ----
  {
    const int w = t >> 6;
    const int lane = t & 63;
    const int r = lane & 15, q = lane >> 4;
    const int hoff = (w & 1) << 4;        // output row tile
    const int dt0 = (w >> 1) * 4;         // 4 d-tiles per wave
    // A-fragment: attn[(hoff+r)][8q + j], j=0..7 (f32 -> split bf16 in regs)
    const float* srow = &S[(hoff + r) * SSTR + 8 * q];
    union { ushort u[8]; bf16x8 v; } Ahi, Alo;
    #pragma unroll
    for (int j = 0; j < 8; ++j) {
      const float a = srow[j];
      const ushort h = f2bf(a);
      Ahi.u[j] = h;
      Alo.u[j] = f2bf(a - bf2f(h));
    }
    float* obase = out + (size_t)pos * DPOS;
    #pragma unroll
    for (int dt = dt0; dt < dt0 + 4; ++dt) {
      const int d = 16 * dt + r;
      const int pq = (q + (d >> 2)) & 3;  // undo granule rotation
      const bf16x8 b = *reinterpret_cast<const bf16x8*>(&Yt[d * YTSTR + pq * 8]);
      f32x4 acc = {0.f, 0.f, 0.f, 0.f};
      acc = __builtin_amdgcn_mfma_f32_16x16x32_bf16(Ahi.v, b, acc, 0, 0, 0);
      acc = __builtin_amdgcn_mfma_f32_16x16x32_bf16(Alo.v, b, acc, 0, 0, 0);
      float* op = obase + (hoff + 4 * q) * HD + d;
      op[0 * HD] = acc[0];
      op[1 * HD] = acc[1];
      op[2 * HD] = acc[2];
      op[3 * HD] = acc[3];
    }
  }
}

extern "C" void kernel_launch(void* const* d_in, const int* in_sizes, int n_in,
                              void* d_out, int out_size, void* d_ws, size_t ws_size,
                              hipStream_t stream) {
  const float* x   = reinterpret_cast<const float*>(d_in[0]);
  const float* pat = reinterpret_cast<const float*>(d_in[1]);
  float* out       = reinterpret_cast<float*>(d_out);
  const int n_pos = in_sizes[0] / DPOS;   // B*L = 16384
  fq_attn_kernel<<<dim3(n_pos), dim3(256), 0, stream>>>(x, pat, out);
}